// Round 1
// baseline (263.880 us; speedup 1.0000x reference)
//
#include <hip/hip_runtime.h>

// Problem constants (fixed by setup_inputs): B=4096, D=512, H=W=64, N=4096.
#define B_ROWS 4096
#define N_COLS 4096
#define DIM    512

// Monotone map: float -> uint32 such that uint compare == float compare.
// val is packed in high 32 bits, index in low 32 -> u64 atomicMin gives
// argmin with smallest-index tie-break (matches numpy argmin).
__device__ __forceinline__ unsigned long long pack_key(float v, int idx) {
    unsigned u = __float_as_uint(v);
    u = (u & 0x80000000u) ? ~u : (u | 0x80000000u);
    return ((unsigned long long)u << 32) | (unsigned)idx;
}

// One wave per row: ||x||^2 for rows < B_ROWS, ||w||^2 otherwise.
// Also (re)initializes the packed argmin accumulators (ws is re-poisoned
// to 0xAA before every timed launch, so this must run every call).
__global__ __launch_bounds__(64) void som_precompute(
    const float* __restrict__ X, const float* __restrict__ Wt,
    float* __restrict__ x_sq, float* __restrict__ w_sq,
    unsigned long long* __restrict__ packed)
{
    int row  = blockIdx.x;      // 0 .. 8191
    int lane = threadIdx.x;     // 0 .. 63
    const float* src = (row < B_ROWS) ? (X + (size_t)row * DIM)
                                      : (Wt + (size_t)(row - B_ROWS) * DIM);
    const float4* s4 = (const float4*)src + lane * 2;
    float4 p = s4[0];
    float4 q = s4[1];
    float s = p.x*p.x + p.y*p.y + p.z*p.z + p.w*p.w
            + q.x*q.x + q.y*q.y + q.z*q.z + q.w*q.w;
    #pragma unroll
    for (int off = 32; off >= 1; off >>= 1)
        s += __shfl_down(s, off, 64);
    if (lane == 0) {
        if (row < B_ROWS) { x_sq[row] = s; packed[row] = ~0ull; }
        else              { w_sq[row - B_ROWS] = s; }
    }
}

// 128x128 fp32 register-tiled GEMM with fused per-row argmin of
// (||w||^2 - 2 x.w). 256 threads, 8x8 accumulators per thread.
#define BM 128
#define BN 128
#define BK 16
#define LDP (BM + 4)   // pad keeps write conflicts at free 2-way; 16B-aligned rows

__global__ __launch_bounds__(256) void som_dist(
    const float* __restrict__ X, const float* __restrict__ Wt,
    const float* __restrict__ w_sq, unsigned long long* __restrict__ packed)
{
    __shared__ float As[BK][LDP];
    __shared__ float Bs[BK][LDP];
    const int tid = threadIdx.x;
    const int bm = blockIdx.y, bn = blockIdx.x;
    const int r  = tid >> 2;   // 0..63 (staging row)
    const int c4 = tid & 3;    // 0..3  (staging float4 column)
    const int ty = tid >> 4;   // 0..15 (compute row group)
    const int tx = tid & 15;   // 0..15 (compute col group)

    const float* Ag = X  + (size_t)(bm * BM + r) * DIM + c4 * 4;
    const float* Bg = Wt + (size_t)(bn * BN + r) * DIM + c4 * 4;

    float acc[8][8];
    #pragma unroll
    for (int i = 0; i < 8; ++i)
        #pragma unroll
        for (int j = 0; j < 8; ++j) acc[i][j] = 0.f;

    for (int k0 = 0; k0 < DIM; k0 += BK) {
        float4 a0 = *(const float4*)(Ag + k0);
        float4 a1 = *(const float4*)(Ag + k0 + (size_t)64 * DIM);
        float4 b0 = *(const float4*)(Bg + k0);
        float4 b1 = *(const float4*)(Bg + k0 + (size_t)64 * DIM);
        __syncthreads();   // previous tile fully consumed
        As[c4*4+0][r]    = a0.x; As[c4*4+1][r]    = a0.y;
        As[c4*4+2][r]    = a0.z; As[c4*4+3][r]    = a0.w;
        As[c4*4+0][r+64] = a1.x; As[c4*4+1][r+64] = a1.y;
        As[c4*4+2][r+64] = a1.z; As[c4*4+3][r+64] = a1.w;
        Bs[c4*4+0][r]    = b0.x; Bs[c4*4+1][r]    = b0.y;
        Bs[c4*4+2][r]    = b0.z; Bs[c4*4+3][r]    = b0.w;
        Bs[c4*4+0][r+64] = b1.x; Bs[c4*4+1][r+64] = b1.y;
        Bs[c4*4+2][r+64] = b1.z; Bs[c4*4+3][r+64] = b1.w;
        __syncthreads();
        #pragma unroll
        for (int k = 0; k < BK; ++k) {
            float4 av0 = *(const float4*)&As[k][ty*8];
            float4 av1 = *(const float4*)&As[k][ty*8+4];
            float4 bv0 = *(const float4*)&Bs[k][tx*8];
            float4 bv1 = *(const float4*)&Bs[k][tx*8+4];
            float a[8] = {av0.x,av0.y,av0.z,av0.w,av1.x,av1.y,av1.z,av1.w};
            float b[8] = {bv0.x,bv0.y,bv0.z,bv0.w,bv1.x,bv1.y,bv1.z,bv1.w};
            #pragma unroll
            for (int i = 0; i < 8; ++i)
                #pragma unroll
                for (int j = 0; j < 8; ++j)
                    acc[i][j] = fmaf(a[i], b[j], acc[i][j]);
        }
    }

    // Epilogue: per-row argmin of (w_sq - 2*dot) over this block's 128 cols.
    const int col0 = bn * BN + tx * 8;
    float wq[8];
    #pragma unroll
    for (int j = 0; j < 8; ++j) wq[j] = w_sq[col0 + j];

    #pragma unroll
    for (int i = 0; i < 8; ++i) {
        unsigned long long best = pack_key(fmaf(-2.f, acc[i][0], wq[0]), col0);
        #pragma unroll
        for (int j = 1; j < 8; ++j) {
            unsigned long long c = pack_key(fmaf(-2.f, acc[i][j], wq[j]), col0 + j);
            best = (c < best) ? c : best;
        }
        // reduce across the 16 tx lanes (xor masks < 16 stay in-group)
        #pragma unroll
        for (int m = 8; m >= 1; m >>= 1) {
            unsigned long long o = __shfl_xor(best, m, 64);
            best = (o < best) ? o : best;
        }
        if (tx == 0)
            atomicMin(&packed[bm * BM + ty * 8 + i], best);
    }
}

// Unpack argmin, compute qe = sqrt(max(||x||^2 + val, 0)), write outputs.
// d_out layout: bmu_indices (4096 x 2) flat, then qe (4096), all as float.
__global__ __launch_bounds__(256) void som_finalize(
    const unsigned long long* __restrict__ packed,
    const float* __restrict__ x_sq, float* __restrict__ out)
{
    int b = blockIdx.x * 256 + threadIdx.x;  // 0..4095
    unsigned long long p = packed[b];
    unsigned idx = (unsigned)(p & 0xffffffffull);
    unsigned key = (unsigned)(p >> 32);
    unsigned u = (key & 0x80000000u) ? (key & 0x7fffffffu) : ~key;
    float val = __uint_as_float(u);
    float sq = fmaxf(x_sq[b] + val, 0.f);
    float qe = sqrtf(sq);
    out[2*b]     = (float)(idx >> 6);   // y = idx / 64
    out[2*b + 1] = (float)(idx & 63);   // x = idx % 64
    out[2*B_ROWS + b] = qe;
}

extern "C" void kernel_launch(void* const* d_in, const int* in_sizes, int n_in,
                              void* d_out, int out_size, void* d_ws, size_t ws_size,
                              hipStream_t stream) {
    const float* X  = (const float*)d_in[0];   // (4096, 512)
    const float* Wt = (const float*)d_in[1];   // (64, 64, 512) -> (4096, 512)
    float* out = (float*)d_out;

    // workspace layout: [0,32K) packed u64[4096]; [32K,48K) x_sq; [48K,64K) w_sq
    unsigned long long* packed = (unsigned long long*)d_ws;
    float* x_sq = (float*)((char*)d_ws + 32768);
    float* w_sq = (float*)((char*)d_ws + 32768 + 16384);

    som_precompute<<<dim3(B_ROWS + N_COLS), dim3(64), 0, stream>>>(X, Wt, x_sq, w_sq, packed);
    som_dist<<<dim3(N_COLS / BN, B_ROWS / BM), dim3(256), 0, stream>>>(X, Wt, w_sq, packed);
    som_finalize<<<dim3(B_ROWS / 256), dim3(256), 0, stream>>>(packed, x_sq, out);
}

// Round 2
// 130.274 us; speedup vs baseline: 2.0256x; 2.0256x over previous
//
#include <hip/hip_runtime.h>

// Problem constants (fixed by setup_inputs): B=4096, D=512, H=W=64, N=4096.
#define B_ROWS 4096
#define N_COLS 4096
#define DIM    512
#define LDK    1024   // row stride (elements) of split bf16 arrays [hi(512) | lo(512)]

typedef __attribute__((ext_vector_type(8))) short short8;
typedef __attribute__((ext_vector_type(4))) float floatx4;

// bf16 round-to-nearest-even split helpers (bit-exact, no API dependence)
__device__ __forceinline__ unsigned short f2bf_rn(float f) {
    unsigned u = __float_as_uint(f);
    u += 0x7fffu + ((u >> 16) & 1u);
    return (unsigned short)(u >> 16);
}
__device__ __forceinline__ float bf2f(unsigned short h) {
    return __uint_as_float(((unsigned)h) << 16);
}

// Monotone float->uint map; (key<<32)|idx gives u64 atomicMin argmin with
// smallest-index tie-break (matches numpy argmin semantics).
__device__ __forceinline__ unsigned long long pack_key(float v, int idx) {
    unsigned u = __float_as_uint(v);
    u = (u & 0x80000000u) ? ~u : (u | 0x80000000u);
    return ((unsigned long long)u << 32) | (unsigned)idx;
}

// Async global->LDS, 16B per lane. LDS dest is wave-uniform base + lane*16.
__device__ __forceinline__ void async16(const unsigned short* g, unsigned short* l) {
    __builtin_amdgcn_global_load_lds(
        (__attribute__((address_space(1))) void*)g,
        (__attribute__((address_space(3))) void*)l, 16, 0, 0);
}

// One wave per row (4 rows/block): split fp32 row into bf16 hi/lo halves,
// compute exact fp32 ||row||^2, init packed argmin accumulators.
__global__ __launch_bounds__(256) void som_convert(
    const float* __restrict__ X, const float* __restrict__ Wt,
    unsigned short* __restrict__ Xc, unsigned short* __restrict__ Wc,
    float* __restrict__ x_sq, float* __restrict__ w_sq,
    unsigned long long* __restrict__ packed)
{
    int wave = threadIdx.x >> 6, lane = threadIdx.x & 63;
    int grow = blockIdx.x * 4 + wave;            // 0..8191
    bool isX = grow < B_ROWS;
    const float* src = isX ? (X + (size_t)grow * DIM)
                           : (Wt + (size_t)(grow - B_ROWS) * DIM);
    const float4* p4 = (const float4*)src;
    float4 a = p4[lane * 2], b = p4[lane * 2 + 1];
    float f[8] = {a.x, a.y, a.z, a.w, b.x, b.y, b.z, b.w};
    unsigned short hi[8], lo[8];
    float s = 0.f;
    #pragma unroll
    for (int t = 0; t < 8; ++t) {
        hi[t] = f2bf_rn(f[t]);
        lo[t] = f2bf_rn(f[t] - bf2f(hi[t]));
        s = fmaf(f[t], f[t], s);
    }
    unsigned short* dst = (isX ? Xc + (size_t)grow * LDK
                               : Wc + (size_t)(grow - B_ROWS) * LDK) + lane * 8;
    *(ushort4*)(dst)       = make_ushort4(hi[0], hi[1], hi[2], hi[3]);
    *(ushort4*)(dst + 4)   = make_ushort4(hi[4], hi[5], hi[6], hi[7]);
    *(ushort4*)(dst + 512) = make_ushort4(lo[0], lo[1], lo[2], lo[3]);
    *(ushort4*)(dst + 516) = make_ushort4(lo[4], lo[5], lo[6], lo[7]);
    #pragma unroll
    for (int off = 32; off >= 1; off >>= 1) s += __shfl_xor(s, off, 64);
    if (lane == 0) {
        if (isX) { x_sq[grow] = s; packed[grow] = ~0ull; }
        else     { w_sq[grow - B_ROWS] = s; }
    }
}

// Split-bf16 distance GEMM + fused per-row argmin.
// 128x128 tile, BK=32, mfma_f32_16x16x32_bf16, 4 waves (2x2), 4x4 MFMA
// tiles/wave. 3 K-passes: (Xh,Wh), (Xh,Wl), (Xl,Wh)  => fp32-grade dot.
__global__ __launch_bounds__(256, 3) void som_dist_bf16(
    const unsigned short* __restrict__ Xc, const unsigned short* __restrict__ Wc,
    const float* __restrict__ w_sq, unsigned long long* __restrict__ packed)
{
    __shared__ unsigned short As[128 * 32];   // row-major, 32 elems (64 B)/row
    __shared__ unsigned short Bs[128 * 32];
    const int tid  = threadIdx.x;
    const int wave = tid >> 6, lane = tid & 63;
    const int wr = wave >> 1, wc = wave & 1;       // 2x2 wave grid
    const int bm = blockIdx.y, bn = blockIdx.x;
    const int quad = lane >> 4, t16 = lane & 15;

    // Staging: wave stages A rows [wave*32, wave*32+32) and same B rows,
    // as 2+2 wave-contiguous 1024B chunks (16 rows x 64 B each).
    const int srow = lane >> 2;          // 0..15
    const int scol = (lane & 3) * 8;     // element offset (16 B granules)
    const unsigned short* gA = Xc + (size_t)(bm * 128 + wave * 32 + srow) * LDK + scol;
    const unsigned short* gB = Wc + (size_t)(bn * 128 + wave * 32 + srow) * LDK + scol;
    unsigned short* lA0 = &As[(wave * 32 + 0)  * 32];
    unsigned short* lA1 = &As[(wave * 32 + 16) * 32];
    unsigned short* lB0 = &Bs[(wave * 32 + 0)  * 32];
    unsigned short* lB1 = &Bs[(wave * 32 + 16) * 32];

    // Fragment read pointers (conflict-free: each wave reads contiguous 1KB)
    const unsigned short* pa = &As[(wr * 64 + t16) * 32 + quad * 8];
    const unsigned short* pb = &Bs[(wc * 64 + t16) * 32 + quad * 8];

    floatx4 acc[4][4];
    #pragma unroll
    for (int i = 0; i < 4; ++i)
        #pragma unroll
        for (int j = 0; j < 4; ++j) acc[i][j] = (floatx4){0.f, 0.f, 0.f, 0.f};

    const int aoffs[3] = {0, 0, 512};
    const int boffs[3] = {0, 512, 0};

    #pragma unroll 1
    for (int p = 0; p < 3; ++p) {
        const unsigned short* gAp = gA + aoffs[p];
        const unsigned short* gBp = gB + boffs[p];
        #pragma unroll 1
        for (int k0 = 0; k0 < DIM; k0 += 32) {
            __syncthreads();                       // prev tile fully consumed
            async16(gAp + k0,            lA0);
            async16(gAp + k0 + 16 * LDK, lA1);
            async16(gBp + k0,            lB0);
            async16(gBp + k0 + 16 * LDK, lB1);
            __syncthreads();                       // staged data visible
            short8 a[4], b[4];
            #pragma unroll
            for (int i = 0; i < 4; ++i) a[i] = *(const short8*)(pa + i * 16 * 32);
            #pragma unroll
            for (int j = 0; j < 4; ++j) b[j] = *(const short8*)(pb + j * 16 * 32);
            #pragma unroll
            for (int i = 0; i < 4; ++i)
                #pragma unroll
                for (int j = 0; j < 4; ++j)
                    acc[i][j] = __builtin_amdgcn_mfma_f32_16x16x32_bf16(
                        a[i], b[j], acc[i][j], 0, 0, 0);
        }
    }

    // Epilogue: val = w_sq - 2*dot (x_sq is per-row constant, irrelevant to
    // argmin). C/D layout: col = t16, row = quad*4 + reg  [m89/m91].
    const int col0 = bn * 128 + wc * 64 + t16;
    float wq[4];
    #pragma unroll
    for (int j = 0; j < 4; ++j) wq[j] = w_sq[col0 + j * 16];
    const int row_base = bm * 128 + wr * 64 + quad * 4;
    #pragma unroll
    for (int i = 0; i < 4; ++i) {
        #pragma unroll
        for (int r = 0; r < 4; ++r) {
            unsigned long long best = ~0ull;
            #pragma unroll
            for (int j = 0; j < 4; ++j) {
                float val = fmaf(-2.f, acc[i][j][r], wq[j]);
                unsigned long long key = pack_key(val, col0 + j * 16);
                best = (key < best) ? key : best;
            }
            #pragma unroll
            for (int m = 1; m <= 8; m <<= 1) {     // reduce 16-lane col group
                unsigned long long o = __shfl_xor(best, m, 64);
                best = (o < best) ? o : best;
            }
            if (t16 == 0)
                atomicMin(&packed[row_base + i * 16 + r], best);
        }
    }
}

// Unpack argmin, qe = sqrt(max(||x||^2 + val, 0)).
// d_out: bmu_indices (4096 x 2) flat, then qe (4096), all float.
__global__ __launch_bounds__(256) void som_finalize(
    const unsigned long long* __restrict__ packed,
    const float* __restrict__ x_sq, float* __restrict__ out)
{
    int b = blockIdx.x * 256 + threadIdx.x;  // 0..4095
    unsigned long long p = packed[b];
    unsigned idx = (unsigned)(p & 0xffffffffull);
    unsigned key = (unsigned)(p >> 32);
    unsigned u = (key & 0x80000000u) ? (key & 0x7fffffffu) : ~key;
    float val = __uint_as_float(u);
    float sq = fmaxf(x_sq[b] + val, 0.f);
    out[2 * b]     = (float)(idx >> 6);   // y = idx / 64
    out[2 * b + 1] = (float)(idx & 63);   // x = idx % 64
    out[2 * B_ROWS + b] = sqrtf(sq);
}

extern "C" void kernel_launch(void* const* d_in, const int* in_sizes, int n_in,
                              void* d_out, int out_size, void* d_ws, size_t ws_size,
                              hipStream_t stream) {
    const float* X  = (const float*)d_in[0];   // (4096, 512)
    const float* Wt = (const float*)d_in[1];   // (64, 64, 512) -> (4096, 512)
    float* out = (float*)d_out;

    // ws layout: [0,32K) packed u64[4096]; [32K,48K) x_sq; [48K,64K) w_sq;
    // [64K, 64K+8M) Xc bf16 split; [64K+8M, 64K+16M) Wc bf16 split.
    unsigned long long* packed = (unsigned long long*)d_ws;
    float* x_sq = (float*)((char*)d_ws + (32 << 10));
    float* w_sq = (float*)((char*)d_ws + (48 << 10));
    unsigned short* Xc = (unsigned short*)((char*)d_ws + (64 << 10));
    unsigned short* Wc = (unsigned short*)((char*)d_ws + (64 << 10) + ((size_t)B_ROWS * LDK * 2));

    som_convert<<<dim3((B_ROWS + N_COLS) / 4), dim3(256), 0, stream>>>(
        X, Wt, Xc, Wc, x_sq, w_sq, packed);
    som_dist_bf16<<<dim3(N_COLS / 128, B_ROWS / 128), dim3(256), 0, stream>>>(
        Xc, Wc, w_sq, packed);
    som_finalize<<<dim3(B_ROWS / 256), dim3(256), 0, stream>>>(packed, x_sq, out);
}

// Round 3
// 123.428 us; speedup vs baseline: 2.1379x; 1.0555x over previous
//
#include <hip/hip_runtime.h>

// Problem constants (fixed by setup_inputs): B=4096, D=512, H=W=64, N=4096.
#define B_ROWS 4096
#define N_COLS 4096
#define DIM    512
#define LDK    1024   // row stride (elements) of split bf16 arrays [hi(512) | lo(512)]

typedef __attribute__((ext_vector_type(8))) short short8;
typedef __attribute__((ext_vector_type(4))) float floatx4;

// bf16 round-to-nearest-even split helpers (bit-exact, no API dependence)
__device__ __forceinline__ unsigned short f2bf_rn(float f) {
    unsigned u = __float_as_uint(f);
    u += 0x7fffu + ((u >> 16) & 1u);
    return (unsigned short)(u >> 16);
}
__device__ __forceinline__ float bf2f(unsigned short h) {
    return __uint_as_float(((unsigned)h) << 16);
}

// Monotone float->uint map; (key<<32)|idx gives u64 atomicMin argmin with
// smallest-index tie-break (matches numpy argmin semantics).
__device__ __forceinline__ unsigned long long pack_key(float v, int idx) {
    unsigned u = __float_as_uint(v);
    u = (u & 0x80000000u) ? ~u : (u | 0x80000000u);
    return ((unsigned long long)u << 32) | (unsigned)idx;
}

// Async global->LDS, 16B per lane. LDS dest is wave-uniform base + lane*16.
__device__ __forceinline__ void async16(const unsigned short* g, unsigned short* l) {
    __builtin_amdgcn_global_load_lds(
        (__attribute__((address_space(1))) void*)g,
        (__attribute__((address_space(3))) void*)l, 16, 0, 0);
}

// One wave per row (4 rows/block): split fp32 row into bf16 hi/lo halves,
// compute exact fp32 ||row||^2, init packed argmin accumulators.
__global__ __launch_bounds__(256) void som_convert(
    const float* __restrict__ X, const float* __restrict__ Wt,
    unsigned short* __restrict__ Xc, unsigned short* __restrict__ Wc,
    float* __restrict__ x_sq, float* __restrict__ w_sq,
    unsigned long long* __restrict__ packed)
{
    int wave = threadIdx.x >> 6, lane = threadIdx.x & 63;
    int grow = blockIdx.x * 4 + wave;            // 0..8191
    bool isX = grow < B_ROWS;
    const float* src = isX ? (X + (size_t)grow * DIM)
                           : (Wt + (size_t)(grow - B_ROWS) * DIM);
    const float4* p4 = (const float4*)src;
    float4 a = p4[lane * 2], b = p4[lane * 2 + 1];
    float f[8] = {a.x, a.y, a.z, a.w, b.x, b.y, b.z, b.w};
    unsigned short hi[8], lo[8];
    float s = 0.f;
    #pragma unroll
    for (int t = 0; t < 8; ++t) {
        hi[t] = f2bf_rn(f[t]);
        lo[t] = f2bf_rn(f[t] - bf2f(hi[t]));
        s = fmaf(f[t], f[t], s);
    }
    unsigned short* dst = (isX ? Xc + (size_t)grow * LDK
                               : Wc + (size_t)(grow - B_ROWS) * LDK) + lane * 8;
    *(ushort4*)(dst)       = make_ushort4(hi[0], hi[1], hi[2], hi[3]);
    *(ushort4*)(dst + 4)   = make_ushort4(hi[4], hi[5], hi[6], hi[7]);
    *(ushort4*)(dst + 512) = make_ushort4(lo[0], lo[1], lo[2], lo[3]);
    *(ushort4*)(dst + 516) = make_ushort4(lo[4], lo[5], lo[6], lo[7]);
    #pragma unroll
    for (int off = 32; off >= 1; off >>= 1) s += __shfl_xor(s, off, 64);
    if (lane == 0) {
        if (isX) { x_sq[grow] = s; packed[grow] = ~0ull; }
        else     { w_sq[grow - B_ROWS] = s; }
    }
}

// Split-bf16 distance GEMM + fused per-row argmin, MERGED 3-product K-loop:
// acc += ah*bh + ah*bl + al*bh per BK=32 iteration (16 iterations total,
// 48 MFMAs/wave per barrier instead of 16).
__global__ __launch_bounds__(256, 3) void som_dist_bf16(
    const unsigned short* __restrict__ Xc, const unsigned short* __restrict__ Wc,
    const float* __restrict__ w_sq, unsigned long long* __restrict__ packed)
{
    __shared__ unsigned short Ah[128 * 32];   // row-major, 32 elems (64 B)/row
    __shared__ unsigned short Al[128 * 32];
    __shared__ unsigned short Bh[128 * 32];
    __shared__ unsigned short Bl[128 * 32];
    const int tid  = threadIdx.x;
    const int wave = tid >> 6, lane = tid & 63;
    const int wr = wave >> 1, wc = wave & 1;       // 2x2 wave grid
    const int bm = blockIdx.y, bn = blockIdx.x;
    const int quad = lane >> 4, t16 = lane & 15;

    // Staging: wave stages rows [wave*32, wave*32+32) of all four tiles as
    // wave-contiguous 1024B chunks (16 rows x 64 B each), 8 async16/iter.
    const int srow = lane >> 2;          // 0..15
    const int scol = (lane & 3) * 8;     // element offset (16 B granules)
    const unsigned short* gAh = Xc + (size_t)(bm * 128 + wave * 32 + srow) * LDK + scol;
    const unsigned short* gBh = Wc + (size_t)(bn * 128 + wave * 32 + srow) * LDK + scol;
    const unsigned short* gAl = gAh + 512;
    const unsigned short* gBl = gBh + 512;
    unsigned short* lAh = &Ah[(wave * 32) * 32];
    unsigned short* lAl = &Al[(wave * 32) * 32];
    unsigned short* lBh = &Bh[(wave * 32) * 32];
    unsigned short* lBl = &Bl[(wave * 32) * 32];

    // Fragment read pointers (each wave reads contiguous 1KB rows)
    const unsigned short* pah = &Ah[(wr * 64 + t16) * 32 + quad * 8];
    const unsigned short* pal = &Al[(wr * 64 + t16) * 32 + quad * 8];
    const unsigned short* pbh = &Bh[(wc * 64 + t16) * 32 + quad * 8];
    const unsigned short* pbl = &Bl[(wc * 64 + t16) * 32 + quad * 8];

    floatx4 acc[4][4];
    #pragma unroll
    for (int i = 0; i < 4; ++i)
        #pragma unroll
        for (int j = 0; j < 4; ++j) acc[i][j] = (floatx4){0.f, 0.f, 0.f, 0.f};

    #pragma unroll 1
    for (int k0 = 0; k0 < DIM; k0 += 32) {
        __syncthreads();                       // prev tile fully consumed
        async16(gAh + k0,            lAh);
        async16(gAh + k0 + 16 * LDK, lAh + 16 * 32);
        async16(gAl + k0,            lAl);
        async16(gAl + k0 + 16 * LDK, lAl + 16 * 32);
        async16(gBh + k0,            lBh);
        async16(gBh + k0 + 16 * LDK, lBh + 16 * 32);
        async16(gBl + k0,            lBl);
        async16(gBl + k0 + 16 * LDK, lBl + 16 * 32);
        __syncthreads();                       // staged data visible

        short8 ah[4], bh[4], x[4];
        #pragma unroll
        for (int i = 0; i < 4; ++i) ah[i] = *(const short8*)(pah + i * 16 * 32);
        #pragma unroll
        for (int j = 0; j < 4; ++j) bh[j] = *(const short8*)(pbh + j * 16 * 32);
        #pragma unroll
        for (int i = 0; i < 4; ++i)
            #pragma unroll
            for (int j = 0; j < 4; ++j)
                acc[i][j] = __builtin_amdgcn_mfma_f32_16x16x32_bf16(
                    ah[i], bh[j], acc[i][j], 0, 0, 0);

        #pragma unroll
        for (int j = 0; j < 4; ++j) x[j] = *(const short8*)(pbl + j * 16 * 32);
        #pragma unroll
        for (int i = 0; i < 4; ++i)
            #pragma unroll
            for (int j = 0; j < 4; ++j)
                acc[i][j] = __builtin_amdgcn_mfma_f32_16x16x32_bf16(
                    ah[i], x[j], acc[i][j], 0, 0, 0);

        #pragma unroll
        for (int i = 0; i < 4; ++i) x[i] = *(const short8*)(pal + i * 16 * 32);
        #pragma unroll
        for (int i = 0; i < 4; ++i)
            #pragma unroll
            for (int j = 0; j < 4; ++j)
                acc[i][j] = __builtin_amdgcn_mfma_f32_16x16x32_bf16(
                    x[i], bh[j], acc[i][j], 0, 0, 0);
    }

    // Epilogue: val = w_sq - 2*dot (x_sq is per-row constant, irrelevant to
    // argmin). C/D layout: col = t16, row = quad*4 + reg  [m89/m91].
    const int col0 = bn * 128 + wc * 64 + t16;
    float wq[4];
    #pragma unroll
    for (int j = 0; j < 4; ++j) wq[j] = w_sq[col0 + j * 16];
    const int row_base = bm * 128 + wr * 64 + quad * 4;
    #pragma unroll
    for (int i = 0; i < 4; ++i) {
        #pragma unroll
        for (int r = 0; r < 4; ++r) {
            unsigned long long best = ~0ull;
            #pragma unroll
            for (int j = 0; j < 4; ++j) {
                float val = fmaf(-2.f, acc[i][j][r], wq[j]);
                unsigned long long key = pack_key(val, col0 + j * 16);
                best = (key < best) ? key : best;
            }
            #pragma unroll
            for (int m = 1; m <= 8; m <<= 1) {     // reduce 16-lane col group
                unsigned long long o = __shfl_xor(best, m, 64);
                best = (o < best) ? o : best;
            }
            if (t16 == 0)
                atomicMin(&packed[row_base + i * 16 + r], best);
        }
    }
}

// Unpack argmin, qe = sqrt(max(||x||^2 + val, 0)).
// d_out: bmu_indices (4096 x 2) flat, then qe (4096), all float.
__global__ __launch_bounds__(256) void som_finalize(
    const unsigned long long* __restrict__ packed,
    const float* __restrict__ x_sq, float* __restrict__ out)
{
    int b = blockIdx.x * 256 + threadIdx.x;  // 0..4095
    unsigned long long p = packed[b];
    unsigned idx = (unsigned)(p & 0xffffffffull);
    unsigned key = (unsigned)(p >> 32);
    unsigned u = (key & 0x80000000u) ? (key & 0x7fffffffu) : ~key;
    float val = __uint_as_float(u);
    float sq = fmaxf(x_sq[b] + val, 0.f);
    out[2 * b]     = (float)(idx >> 6);   // y = idx / 64
    out[2 * b + 1] = (float)(idx & 63);   // x = idx % 64
    out[2 * B_ROWS + b] = sqrtf(sq);
}

extern "C" void kernel_launch(void* const* d_in, const int* in_sizes, int n_in,
                              void* d_out, int out_size, void* d_ws, size_t ws_size,
                              hipStream_t stream) {
    const float* X  = (const float*)d_in[0];   // (4096, 512)
    const float* Wt = (const float*)d_in[1];   // (64, 64, 512) -> (4096, 512)
    float* out = (float*)d_out;

    // ws layout: [0,32K) packed u64[4096]; [32K,48K) x_sq; [48K,64K) w_sq;
    // [64K, 64K+8M) Xc bf16 split; [64K+8M, 64K+16M) Wc bf16 split.
    unsigned long long* packed = (unsigned long long*)d_ws;
    float* x_sq = (float*)((char*)d_ws + (32 << 10));
    float* w_sq = (float*)((char*)d_ws + (48 << 10));
    unsigned short* Xc = (unsigned short*)((char*)d_ws + (64 << 10));
    unsigned short* Wc = (unsigned short*)((char*)d_ws + (64 << 10) + ((size_t)B_ROWS * LDK * 2));

    som_convert<<<dim3((B_ROWS + N_COLS) / 4), dim3(256), 0, stream>>>(
        X, Wt, Xc, Wc, x_sq, w_sq, packed);
    som_dist_bf16<<<dim3(N_COLS / 128, B_ROWS / 128), dim3(256), 0, stream>>>(
        Xc, Wc, w_sq, packed);
    som_finalize<<<dim3(B_ROWS / 256), dim3(256), 0, stream>>>(packed, x_sq, out);
}